// Round 3
// baseline (393.477 us; speedup 1.0000x reference)
//
#include <hip/hip_runtime.h>
#include <stdint.h>

#define LOGZERO (-1e10f)

static constexpr int BS    = 32;
static constexpr int XMAX  = 1024;
static constexpr int VOCAB = 1000;
static constexpr int YMAX  = 128;
static constexpr int NROWS = YMAX + 1;     // 129 trigger-mask rows
static constexpr int CH    = 8;            // rows per LDS chunk (g4pack uses >>3)
static constexpr int NPROD = 8;            // producer waves
static constexpr int NWAVES = 1 + NPROD;   // + 1 consumer wave
static constexpr int NPAIR = XMAX / 2;
static constexpr size_t LPWS_BYTES = (size_t)BS * XMAX * 256 * 4;  // 32 MB staged lp

// ---------------- Kernel A: full-chip gather of lp_path ---------------------
// Spreads the divergent vocab-row gathers over 512 blocks (all 256 CUs) so the
// per-CU outstanding-miss limit stops serializing them. Writes, per (b,t),
// the consumer lane layout: float4(vb, va, vb, vc) at lp[b][t][lane*4].
__global__ __launch_bounds__(256) void k_gather(
    const float* __restrict__ ctc, const int* __restrict__ src_size,
    const int* __restrict__ ys, const int* __restrict__ blankp,
    float* __restrict__ lp_ws)
{
    const int blk  = blockIdx.x;
    const int b    = blk >> 4;                 // 16 blocks per batch element
    const int seg  = blk & 15;                 // 64-row segment
    const int wid  = threadIdx.x >> 6;
    const int lane = threadIdx.x & 63;
    const int ss   = src_size[b];
    const int bv   = blankp[0];
    const int tokA = ys[b * YMAX + 2 * lane];
    const int tokB = ys[b * YMAX + 2 * lane + 1];
    const float* baseg = ctc + (size_t)b * XMAX * VOCAB;
    float* basew = lp_ws + (size_t)b * XMAX * 256 + lane * 4;
    const int t0 = seg * 64 + wid * 16;
    #pragma unroll 4
    for (int r = 0; r < 16; ++r) {
        const int t = t0 + r;
        if (t < ss) {
            const float* rp = baseg + (size_t)t * VOCAB;
            float vb = rp[bv], va = rp[tokA], vc = rp[tokB];
            *reinterpret_cast<float4*>(basew + (size_t)t * 256) =
                make_float4(vb, va, vb, vc);
        }
    }
}

// ---------------- Kernel B: producer/consumer Viterbi ring -------------------
// Consumer wave (wid 0): lane i holds states 4i..4i+3; state 256 on lane 0.
// STAGED: producers stream coalesced float4 rows from lp_ws (cheap).
// !STAGED (fallback when ws too small): producers gather from ctc (round-2).
template<bool STAGED>
__global__ __launch_bounds__(64 * NWAVES) void k_viterbi(
    const float* __restrict__ ctc, const float* __restrict__ lp_ws,
    const int* __restrict__ src_size,
    const int* __restrict__ ys, const int* __restrict__ ylens,
    const int* __restrict__ blankp, int* __restrict__ csum_ws,
    float* __restrict__ out)
{
    __shared__ float buf[2][CH][256];              // 16 KB lp ring
    __shared__ unsigned char  bpb[XMAX * 64];      // 64 KB raw 2-bit args x4
    __shared__ unsigned char  g4pack[XMAX / CH];   // 128 B state-256 args, packed
    __shared__ unsigned short bp2[NPAIR * 64];     // 64 KB composed pair nibbles
    __shared__ unsigned char  bp2_256[NPAIR];      // 512 B state-256 pairs
    __shared__ unsigned short st_lds[XMAX];        //  2 KB backtraced states
    __shared__ int ysl[YMAX];

    const int b    = blockIdx.x;
    const int tid  = threadIdx.x;
    const int wid  = tid >> 6;
    const int lane = tid & 63;
    const int ss   = src_size[b];
    const int yl   = ylens[b];
    const int bv   = blankp[0];
    const int plen = 2 * yl + 1;
    const float LZ = LOGZERO;

    for (int j = tid; j < YMAX; j += 64 * NWAVES) ysl[j] = ys[b * YMAX + j];
    for (int t = tid; t < XMAX; t += 64 * NWAVES) st_lds[t] = 0;
    __syncthreads();

    const int nchunk = (ss + CH - 1) / CH;
    const float* baseg = ctc + (size_t)b * XMAX * VOCAB;

    int start = 0;   // set by consumer wave, used by lane 0 chain later

    if (wid == 0) {
        // ---------------- consumer ----------------
        const int tokA = ysl[2 * lane];
        const int tokB = ysl[2 * lane + 1];
        const bool al1 = (lane > 0) && (tokA != ysl[2 * lane - 1]);
        const bool al3 = (tokB != tokA);
        const bool o0 = (4 * lane     >= plen);
        const bool o1 = (4 * lane + 1 >= plen);
        const bool o2 = (4 * lane + 2 >= plen);
        const bool o3 = (4 * lane + 3 >= plen);
        const bool o4 = (256 >= plen);
        const int rotidx = (lane + 63) & 63;

        float a0 = (lane == 0) ? 0.0f : LZ;
        float a1 = LZ, a2 = LZ, a3 = LZ, a4 = LZ;
        float rotp = __shfl(a3, rotidx);           // shfl of a3 entering step 0

        for (int c = 0; c < nchunk; ++c) {
            __builtin_amdgcn_s_barrier();          // chunk c published
            asm volatile("" ::: "memory");
            __builtin_amdgcn_sched_barrier(0);
            const int cb = c & 1;
            float4 q[CH];
            #pragma unroll
            for (int r = 0; r < CH; ++r)
                q[r] = *reinterpret_cast<const float4*>(&buf[cb][r][lane * 4]);
            unsigned int g4acc = 0;
            #pragma unroll
            for (int r = 0; r < CH; ++r) {
                const int t = c * CH + r;
                if (t < ss) {
                    // a3 path first: no shfl dep, feeds next step's shfl
                    float m3 = a3; int g3 = 0;
                    if (a2 > m3) { m3 = a2; g3 = 1; }
                    float sk3 = al3 ? a1 : LZ;
                    if (sk3 > m3) { m3 = sk3; g3 = 2; }
                    float a3n = (o3 ? LZ : m3) + q[r].w;
                    float rot = rotp;
                    rotp = __shfl(a3n, rotidx);    // for next step
                    float p3 = (lane == 0) ? LZ : rot;
                    // strict '>' replicates jnp.argmax first-max tie-break
                    float m0 = a0; int g0 = 0; if (p3 > m0) { m0 = p3; g0 = 1; }
                    float m1 = a1; int g1 = 0; if (a0 > m1) { m1 = a0; g1 = 1; }
                    float sk1 = al1 ? p3 : LZ;  if (sk1 > m1) { m1 = sk1; g1 = 2; }
                    float m2 = a2; int g2 = 0; if (a1 > m2) { m2 = a1; g2 = 1; }
                    float m4 = a4; int g4 = 0; if (rot > m4) { m4 = rot; g4 = 1; }
                    a0 = (o0 ? LZ : m0) + q[r].x;
                    a1 = (o1 ? LZ : m1) + q[r].y;
                    a2 = (o2 ? LZ : m2) + q[r].z;
                    a3 = a3n;
                    a4 = (o4 ? LZ : m4) + q[r].x;  // lp4 == blank lp == q.x
                    g4acc |= (unsigned)g4 << r;
                    bpb[t * 64 + lane] =
                        (unsigned char)(g0 | (g1 << 2) | (g2 << 4) | (g3 << 6));
                }
            }
            if (lane == 0) g4pack[c] = (unsigned char)g4acc;
        }

        // score & start (a4 valid on lane 0 only)
        auto getA = [&](int idx) -> float {
            if (idx == 256) return __shfl(a4, 0);
            int k = idx & 3;
            float pick = (k == 0) ? a0 : (k == 1) ? a1 : (k == 2) ? a2 : a3;
            return __shfl(pick, idx >> 2);
        };
        const float s1v = getA(plen - 1), s2v = getA(plen - 2);
        const float score = (s1v > s2v) ? s1v : s2v;
        start = (s1v > s2v) ? (plen - 1) : (plen - 2);
        if (lane == 0) {
            out[b] = score;                                          // output 0
            out[32 + (size_t)BS * NROWS * XMAX + b] = (float)(yl + 1);   // output 2
        }
    } else if (STAGED) {
        // ------- producers: coalesced float4 stream from staged lp_ws -------
        const int pr = wid - 1;                    // row within chunk
        const float* basew = lp_ws + (size_t)b * XMAX * 256 + lane * 4;
        float4 v0 = *reinterpret_cast<const float4*>(basew + (size_t)pr * 256);
        float4 v1 = *reinterpret_cast<const float4*>(basew + (size_t)(CH + pr) * 256);
        for (int c = 0; c < nchunk; ++c) {
            if (c & 1) {
                *reinterpret_cast<float4*>(&buf[1][pr][lane * 4]) = v1;
                int tn = (c + 2) * CH + pr; if (tn > XMAX - 1) tn = XMAX - 1;
                v1 = *reinterpret_cast<const float4*>(basew + (size_t)tn * 256);
            } else {
                *reinterpret_cast<float4*>(&buf[0][pr][lane * 4]) = v0;
                int tn = (c + 2) * CH + pr; if (tn > XMAX - 1) tn = XMAX - 1;
                v0 = *reinterpret_cast<const float4*>(basew + (size_t)tn * 256);
            }
            // publish chunk c; prefetch loads stay in flight (no vmcnt drain)
            asm volatile("s_waitcnt lgkmcnt(0)" ::: "memory");
            __builtin_amdgcn_s_barrier();
        }
    } else {
        // ------- fallback producers: divergent gather from ctc (round-2) ----
        const int pr = wid - 1;
        const int tokA = ysl[2 * lane];
        const int tokB = ysl[2 * lane + 1];
        int t0 = pr; if (t0 >= ss) t0 = ss - 1;
        const float* r0 = baseg + (size_t)t0 * VOCAB;
        float vb0 = r0[bv], va0 = r0[tokA], vc0 = r0[tokB];
        int t1 = CH + pr; if (t1 >= ss) t1 = ss - 1;
        const float* r1 = baseg + (size_t)t1 * VOCAB;
        float vb1 = r1[bv], va1 = r1[tokA], vc1 = r1[tokB];
        for (int c = 0; c < nchunk; ++c) {
            if (c & 1) {
                *reinterpret_cast<float4*>(&buf[1][pr][lane * 4]) =
                    make_float4(vb1, va1, vb1, vc1);
                int tn = (c + 2) * CH + pr; if (tn >= ss) tn = ss - 1;
                const float* r = baseg + (size_t)tn * VOCAB;
                vb1 = r[bv]; va1 = r[tokA]; vc1 = r[tokB];
            } else {
                *reinterpret_cast<float4*>(&buf[0][pr][lane * 4]) =
                    make_float4(vb0, va0, vb0, vc0);
                int tn = (c + 2) * CH + pr; if (tn >= ss) tn = ss - 1;
                const float* r = baseg + (size_t)tn * VOCAB;
                vb0 = r[bv]; va0 = r[tokA]; vc0 = r[tokB];
            }
            asm volatile("s_waitcnt lgkmcnt(0)" ::: "memory");
            __builtin_amdgcn_s_barrier();
        }
    }
    __syncthreads();   // bpb/g4pack visible to all waves (drains stray loads once)

    // ---- parallel pair-composition across all 9 waves ----
    const int pmax = (ss - 1) >> 1;                // pairs used: p in [1, pmax]
    for (int p = 1 + wid; p <= pmax; p += NWAVES) {
        int oOdd  = bpb[(2 * p + 1) * 64 + lane];
        int oEven = bpb[(2 * p) * 64 + lane];
        int uEven = (lane > 0) ? bpb[(2 * p) * 64 + lane - 1] : 0;
        int evenWin = uEven | (oEven << 8);        // states 4l-4..4l+3 of even row
        unsigned int acc = 0;
        #pragma unroll
        for (int k = 0; k < 4; ++k) {
            int a1v = (oOdd >> (2 * k)) & 3;
            int sh  = 2 * k - 2 * a1v + 8;         // bit pos of state s-a1 in window
            int a2v = (evenWin >> sh) & 3;
            acc |= (unsigned)(a1v | (a2v << 2)) << (4 * k);
        }
        bp2[p * 64 + lane] = (unsigned short)acc;
        const int tOdd = 2 * p + 1, tEven = 2 * p;
        int a16 = (g4pack[tOdd >> 3] >> (tOdd & 7)) & 1;
        int a26 = (a16 == 0) ? ((g4pack[tEven >> 3] >> (tEven & 7)) & 1)
                             : ((bpb[tEven * 64 + 63] >> 6) & 3);
        if (lane == 0) bp2_256[p] = (unsigned char)(a16 | (a26 << 2));
    }
    __syncthreads();

    // ---- backtrace: 2 steps per dependent LDS read (lane 0 of wave 0) ----
    if (tid == 0) {
        int s = start, tc = ss - 1;
        st_lds[tc] = (unsigned short)s;
        if ((tc & 1) == 0 && tc >= 1) {            // raw single step on even row tc
            int arg;
            if (s == 256) arg = (g4pack[tc >> 3] >> (tc & 7)) & 1;
            else arg = (bpb[tc * 64 + (s >> 2)] >> ((s & 3) * 2)) & 3;
            s -= arg; --tc; st_lds[tc] = (unsigned short)s;
        }
        while (tc > 1) {                           // tc odd: pair p = tc>>1
            int n;
            if (s == 256) n = bp2_256[tc >> 1];
            else n = (bp2[(tc >> 1) * 64 + (s >> 2)] >> ((s & 3) * 4)) & 0xF;
            int sA = s - (n & 3);
            int sB = sA - (n >> 2);
            st_lds[tc - 1] = (unsigned short)sA;
            st_lds[tc - 2] = (unsigned short)sB;
            s = sB; tc -= 2;
        }
        if (tc == 1) {                             // raw row 1
            int arg;
            if (s == 256) arg = (g4pack[0] >> 1) & 1;
            else arg = (bpb[64 + (s >> 2)] >> ((s & 3) * 2)) & 3;
            s -= arg; st_lds[0] = (unsigned short)s;
        }
    }
    __syncthreads();

    // ---- aligned tokens -> collapse repeats -> csum (wave 0) ----
    if (wid == 0) {
        auto tok_lds = [&](int stv) -> int { return (stv & 1) ? ysl[stv >> 1] : bv; };
        const int t0c = lane * 16;
        int prev_raw = (t0c == 0) ? 0 : tok_lds(st_lds[t0c - 1]);
        int cnt = 0;
        int csl[16];
        #pragma unroll
        for (int i = 0; i < 16; ++i) {
            int raw = tok_lds(st_lds[t0c + i]);
            int ac = (raw == prev_raw) ? 0 : raw;
            prev_raw = raw;
            csl[i] = cnt;
            cnt += (ac != bv) ? 1 : 0;
        }
        int v = cnt;
        #pragma unroll
        for (int off = 1; off < 64; off <<= 1) {
            int u = __shfl_up(v, off);
            if (lane >= off) v += u;
        }
        const int base_c = v - cnt;
        int* co = csum_ws + b * XMAX + t0c;
        #pragma unroll
        for (int i = 0; i < 16; ++i) co[i] = base_c + csl[i];
    }
}

// ---------------- Kernel C: trigger mask as 0/1 floats ----------------------
__global__ __launch_bounds__(256) void k_mask(
    const int* __restrict__ csum_ws, const int* __restrict__ src_size,
    float* __restrict__ out)
{
    int bj = blockIdx.x;
    int b = bj / NROWS, j = bj - b * NROWS;
    int ss = src_size[b];
    const int* cs = csum_ws + b * XMAX;
    float* orow = out + 32 + (size_t)bj * XMAX;
    int t = threadIdx.x * 4;
    float4 v;
    float* vp = &v.x;
    #pragma unroll
    for (int i = 0; i < 4; ++i) {
        int tt = t + i;
        int c = cs[tt];
        bool in = tt < ss;
        bool val;
        if (j < YMAX) val = (c == j) && in;
        else          val = ((c == YMAX) || (tt == ss - 1)) && in;
        vp[i] = val ? 1.0f : 0.0f;
    }
    *(float4*)(orow + t) = v;
}

extern "C" void kernel_launch(void* const* d_in, const int* in_sizes, int n_in,
                              void* d_out, int out_size, void* d_ws, size_t ws_size,
                              hipStream_t stream) {
    const float* ctc      = (const float*)d_in[0];
    // d_in[1] = src_mask (derived from src_size; unused)
    const int*   src_size = (const int*)d_in[2];
    const int*   ys       = (const int*)d_in[3];
    const int*   ylens    = (const int*)d_in[4];
    const int*   blankp   = (const int*)d_in[5];
    float* out = (float*)d_out;

    const size_t need = LPWS_BYTES + (size_t)BS * XMAX * sizeof(int);
    if (ws_size >= need) {
        float* lp_ws   = (float*)d_ws;
        int*   csum_ws = (int*)((char*)d_ws + LPWS_BYTES);
        k_gather<<<BS * 16, 256, 0, stream>>>(ctc, src_size, ys, blankp, lp_ws);
        k_viterbi<true><<<BS, 64 * NWAVES, 0, stream>>>(
            ctc, lp_ws, src_size, ys, ylens, blankp, csum_ws, out);
        k_mask<<<BS * NROWS, 256, 0, stream>>>(csum_ws, src_size, out);
    } else {
        int* csum_ws = (int*)d_ws;   // 32*1024*4 = 128 KB
        k_viterbi<false><<<BS, 64 * NWAVES, 0, stream>>>(
            ctc, nullptr, src_size, ys, ylens, blankp, csum_ws, out);
        k_mask<<<BS * NROWS, 256, 0, stream>>>(csum_ws, src_size, out);
    }
}

// Round 4
// 357.055 us; speedup vs baseline: 1.1020x; 1.1020x over previous
//
#include <hip/hip_runtime.h>
#include <stdint.h>

#define LOGZERO (-1e10f)

static constexpr int BS    = 32;
static constexpr int XMAX  = 1024;
static constexpr int VOCAB = 1000;
static constexpr int YMAX  = 128;
static constexpr int NROWS = YMAX + 1;     // 129 trigger-mask rows
static constexpr int CH    = 8;            // rows per LDS chunk (g4pack uses >>3)
static constexpr int NPROD = 8;            // producer waves
static constexpr int NWAVES = 1 + NPROD;   // + 1 consumer wave
static constexpr int NPAIR = XMAX / 2;
static constexpr size_t LPWS_BYTES = (size_t)BS * XMAX * 256 * 4;  // 32 MB staged lp

// lane i <- lane i-1 (mod 64): v_mov_b32_dpp wave_ror:1 (0x13C). Pure VALU —
// replaces ds_bpermute (__shfl) in the recurrence; no lgkmcnt involvement.
__device__ __forceinline__ float rot1(float x) {
    int r = __builtin_amdgcn_update_dpp(0, __float_as_int(x),
                                        0x13C /*wave_ror:1*/, 0xF, 0xF, false);
    return __int_as_float(r);
}

// ---------------- Kernel A: full-chip gather of lp_path ---------------------
__global__ __launch_bounds__(256) void k_gather(
    const float* __restrict__ ctc, const int* __restrict__ src_size,
    const int* __restrict__ ys, const int* __restrict__ blankp,
    float* __restrict__ lp_ws)
{
    const int blk  = blockIdx.x;
    const int b    = blk >> 4;                 // 16 blocks per batch element
    const int seg  = blk & 15;                 // 64-row segment
    const int wid  = threadIdx.x >> 6;
    const int lane = threadIdx.x & 63;
    const int ss   = src_size[b];
    const int bv   = blankp[0];
    const int tokA = ys[b * YMAX + 2 * lane];
    const int tokB = ys[b * YMAX + 2 * lane + 1];
    const float* baseg = ctc + (size_t)b * XMAX * VOCAB;
    float* basew = lp_ws + (size_t)b * XMAX * 256 + lane * 4;
    const int t0 = seg * 64 + wid * 16;
    #pragma unroll 4
    for (int r = 0; r < 16; ++r) {
        const int t = t0 + r;
        if (t < ss) {
            const float* rp = baseg + (size_t)t * VOCAB;
            float vb = rp[bv], va = rp[tokA], vc = rp[tokB];
            *reinterpret_cast<float4*>(basew + (size_t)t * 256) =
                make_float4(vb, va, vb, vc);
        }
    }
}

// One Viterbi step. Outside-state masks removed (provably dead: inside states
// never read outside states; score/backtrace touch inside states only; the
// reference masks AFTER argmax so backpointers are identical).
#define VSTEP(qq, PK, SHIFT, RBIT) do {                                     \
    float rot = rot1(a3);                      /* a3[l-1]; lane0<-a3[63] */ \
    float p3  = (lane == 0) ? LZ : rot;                                     \
    float sk3 = al3 ? a1 : LZ;                                              \
    float m3 = a3; int g3 = 0;                                              \
    if (a2  > m3) { m3 = a2;  g3 = 1; }                                     \
    if (sk3 > m3) { m3 = sk3; g3 = 2; }                                     \
    float sk1 = al1 ? p3 : LZ;                                              \
    float m1 = a1; int g1 = 0;                                              \
    if (a0  > m1) { m1 = a0;  g1 = 1; }                                     \
    if (sk1 > m1) { m1 = sk1; g1 = 2; }                                     \
    float m0 = a0; int g0 = 0; if (p3  > m0) { m0 = p3;  g0 = 1; }          \
    float m2 = a2; int g2 = 0; if (a1  > m2) { m2 = a1;  g2 = 1; }          \
    float m4 = a4; int g4 = 0; if (rot > m4) { m4 = rot; g4 = 1; }          \
    a0 = m0 + (qq).x; a1 = m1 + (qq).y; a2 = m2 + (qq).z; a3 = m3 + (qq).w; \
    a4 = m4 + (qq).x;                          /* lp4 == blank lp == q.x */ \
    PK |= (unsigned)(g0 | (g1 << 2) | (g2 << 4) | (g3 << 6)) << (SHIFT);    \
    g4acc |= (unsigned)g4 << (RBIT);                                        \
} while (0)

// ---------------- Kernel B: producer/consumer Viterbi ring -------------------
template<bool STAGED>
__global__ __launch_bounds__(64 * NWAVES) void k_viterbi(
    const float* __restrict__ ctc, const float* __restrict__ lp_ws,
    const int* __restrict__ src_size,
    const int* __restrict__ ys, const int* __restrict__ ylens,
    const int* __restrict__ blankp, int* __restrict__ csum_ws,
    float* __restrict__ out)
{
    __shared__ float buf[2][CH][256];              // 16 KB lp ring
    __shared__ unsigned int  bpb32[(XMAX / 4) * 64]; // 64 KB packed args [t/4][lane]
    __shared__ unsigned char  g4pack[XMAX / CH];   // 128 B state-256 args, packed
    __shared__ unsigned short bp2[NPAIR * 64];     // 64 KB composed pair nibbles
    __shared__ unsigned char  bp2_256[NPAIR];      // 512 B state-256 pairs
    __shared__ unsigned short st_lds[XMAX];        //  2 KB backtraced states
    __shared__ int ysl[YMAX];

    const int b    = blockIdx.x;
    const int tid  = threadIdx.x;
    const int wid  = tid >> 6;
    const int lane = tid & 63;
    const int ss   = src_size[b];
    const int yl   = ylens[b];
    const int bv   = blankp[0];
    const int plen = 2 * yl + 1;
    const float LZ = LOGZERO;

    for (int j = tid; j < YMAX; j += 64 * NWAVES) ysl[j] = ys[b * YMAX + j];
    for (int t = tid; t < XMAX; t += 64 * NWAVES) st_lds[t] = 0;
    __syncthreads();

    const int nchunk = (ss + CH - 1) / CH;
    const float* baseg = ctc + (size_t)b * XMAX * VOCAB;

    int start = 0;   // set by consumer wave, used by lane 0 chain later

    if (wid == 0) {
        // ---------------- consumer ----------------
        const int tokA = ysl[2 * lane];
        const int tokB = ysl[2 * lane + 1];
        const bool al1 = (lane > 0) && (tokA != ysl[2 * lane - 1]);
        const bool al3 = (tokB != tokA);

        float a0 = (lane == 0) ? 0.0f : LZ;
        float a1 = LZ, a2 = LZ, a3 = LZ, a4 = LZ;

        const int nfull = ss >> 3;                 // chunks with all 8 steps < ss
        const int mrem  = ss & 7;

        for (int c = 0; c < nfull; ++c) {
            __builtin_amdgcn_s_barrier();          // chunk c published
            asm volatile("" ::: "memory");
            __builtin_amdgcn_sched_barrier(0);
            const int cb = c & 1;
            float4 q[CH];
            #pragma unroll
            for (int r = 0; r < CH; ++r)
                q[r] = *reinterpret_cast<const float4*>(&buf[cb][r][lane * 4]);
            unsigned int pkA = 0, pkB = 0, g4acc = 0;
            #pragma unroll
            for (int r = 0; r < 4; ++r) VSTEP(q[r], pkA, r * 8, r);
            #pragma unroll
            for (int r = 4; r < 8; ++r) VSTEP(q[r], pkB, (r - 4) * 8, r);
            bpb32[(2 * c) * 64 + lane]     = pkA;
            bpb32[(2 * c + 1) * 64 + lane] = pkB;
            if (lane == 0) g4pack[c] = (unsigned char)g4acc;
        }
        if (mrem) {                                // tail chunk (steps < mrem)
            __builtin_amdgcn_s_barrier();
            asm volatile("" ::: "memory");
            __builtin_amdgcn_sched_barrier(0);
            const int cb = nfull & 1;
            float4 q[CH];
            #pragma unroll
            for (int r = 0; r < CH; ++r)
                q[r] = *reinterpret_cast<const float4*>(&buf[cb][r][lane * 4]);
            unsigned int pkA = 0, pkB = 0, g4acc = 0;
            #pragma unroll
            for (int r = 0; r < 4; ++r)
                if (r < mrem) VSTEP(q[r], pkA, r * 8, r);
            #pragma unroll
            for (int r = 4; r < 8; ++r)
                if (r < mrem) VSTEP(q[r], pkB, (r - 4) * 8, r);
            bpb32[(2 * nfull) * 64 + lane] = pkA;
            if (mrem > 4) bpb32[(2 * nfull + 1) * 64 + lane] = pkB;
            if (lane == 0) g4pack[nfull] = (unsigned char)g4acc;
        }

        // score & start (a4 valid on lane 0 only)
        auto getA = [&](int idx) -> float {
            if (idx == 256) return __shfl(a4, 0);
            int k = idx & 3;
            float pick = (k == 0) ? a0 : (k == 1) ? a1 : (k == 2) ? a2 : a3;
            return __shfl(pick, idx >> 2);
        };
        const float s1v = getA(plen - 1), s2v = getA(plen - 2);
        const float score = (s1v > s2v) ? s1v : s2v;
        start = (s1v > s2v) ? (plen - 1) : (plen - 2);
        if (lane == 0) {
            out[b] = score;                                          // output 0
            out[32 + (size_t)BS * NROWS * XMAX + b] = (float)(yl + 1);   // output 2
        }
    } else if (STAGED) {
        // ------- producers: coalesced float4 stream, 4-deep reg prefetch ----
        const int pr = wid - 1;                    // row within chunk
        const float* basew = lp_ws + (size_t)b * XMAX * 256 + lane * 4;
        auto ldrow = [&](int cc) -> float4 {
            int tn = cc * CH + pr; if (tn > XMAX - 1) tn = XMAX - 1;
            return *reinterpret_cast<const float4*>(basew + (size_t)tn * 256);
        };
        float4 v0 = ldrow(0), v1 = ldrow(1), v2 = ldrow(2), v3 = ldrow(3);
        int c = 0;
        for (;;) {
            *reinterpret_cast<float4*>(&buf[c & 1][pr][lane * 4]) = v0;
            v0 = ldrow(c + 4);
            asm volatile("s_waitcnt lgkmcnt(0)" ::: "memory");
            __builtin_amdgcn_s_barrier();
            if (++c >= nchunk) break;
            *reinterpret_cast<float4*>(&buf[c & 1][pr][lane * 4]) = v1;
            v1 = ldrow(c + 4);
            asm volatile("s_waitcnt lgkmcnt(0)" ::: "memory");
            __builtin_amdgcn_s_barrier();
            if (++c >= nchunk) break;
            *reinterpret_cast<float4*>(&buf[c & 1][pr][lane * 4]) = v2;
            v2 = ldrow(c + 4);
            asm volatile("s_waitcnt lgkmcnt(0)" ::: "memory");
            __builtin_amdgcn_s_barrier();
            if (++c >= nchunk) break;
            *reinterpret_cast<float4*>(&buf[c & 1][pr][lane * 4]) = v3;
            v3 = ldrow(c + 4);
            asm volatile("s_waitcnt lgkmcnt(0)" ::: "memory");
            __builtin_amdgcn_s_barrier();
            if (++c >= nchunk) break;
        }
    } else {
        // ------- fallback producers: divergent gather from ctc (round-2) ----
        const int pr = wid - 1;
        const int tokA = ysl[2 * lane];
        const int tokB = ysl[2 * lane + 1];
        int t0 = pr; if (t0 >= ss) t0 = ss - 1;
        const float* r0 = baseg + (size_t)t0 * VOCAB;
        float vb0 = r0[bv], va0 = r0[tokA], vc0 = r0[tokB];
        int t1 = CH + pr; if (t1 >= ss) t1 = ss - 1;
        const float* r1 = baseg + (size_t)t1 * VOCAB;
        float vb1 = r1[bv], va1 = r1[tokA], vc1 = r1[tokB];
        for (int c = 0; c < nchunk; ++c) {
            if (c & 1) {
                *reinterpret_cast<float4*>(&buf[1][pr][lane * 4]) =
                    make_float4(vb1, va1, vb1, vc1);
                int tn = (c + 2) * CH + pr; if (tn >= ss) tn = ss - 1;
                const float* r = baseg + (size_t)tn * VOCAB;
                vb1 = r[bv]; va1 = r[tokA]; vc1 = r[tokB];
            } else {
                *reinterpret_cast<float4*>(&buf[0][pr][lane * 4]) =
                    make_float4(vb0, va0, vb0, vc0);
                int tn = (c + 2) * CH + pr; if (tn >= ss) tn = ss - 1;
                const float* r = baseg + (size_t)tn * VOCAB;
                vb0 = r[bv]; va0 = r[tokA]; vc0 = r[tokB];
            }
            asm volatile("s_waitcnt lgkmcnt(0)" ::: "memory");
            __builtin_amdgcn_s_barrier();
        }
    }
    __syncthreads();   // bpb/g4pack visible to all waves

    // byte (t, laneIdx) of the packed backpointer store
    const unsigned char* bpb8 = reinterpret_cast<const unsigned char*>(bpb32);
    #define BPBYTE(t, l) ((int)bpb8[(((t) >> 2) * 64 + (l)) * 4 + ((t) & 3)])

    // ---- parallel pair-composition across all 9 waves ----
    const int pmax = (ss - 1) >> 1;                // pairs used: p in [1, pmax]
    for (int p = 1 + wid; p <= pmax; p += NWAVES) {
        int oOdd  = BPBYTE(2 * p + 1, lane);
        int oEven = BPBYTE(2 * p, lane);
        int uEven = (lane > 0) ? BPBYTE(2 * p, lane - 1) : 0;
        int evenWin = uEven | (oEven << 8);        // states 4l-4..4l+3 of even row
        unsigned int acc = 0;
        #pragma unroll
        for (int k = 0; k < 4; ++k) {
            int a1v = (oOdd >> (2 * k)) & 3;
            int sh  = 2 * k - 2 * a1v + 8;         // bit pos of state s-a1 in window
            int a2v = (evenWin >> sh) & 3;
            acc |= (unsigned)(a1v | (a2v << 2)) << (4 * k);
        }
        bp2[p * 64 + lane] = (unsigned short)acc;
        const int tOdd = 2 * p + 1, tEven = 2 * p;
        int a16 = (g4pack[tOdd >> 3] >> (tOdd & 7)) & 1;
        int a26 = (a16 == 0) ? ((g4pack[tEven >> 3] >> (tEven & 7)) & 1)
                             : ((BPBYTE(tEven, 63) >> 6) & 3);
        if (lane == 0) bp2_256[p] = (unsigned char)(a16 | (a26 << 2));
    }
    __syncthreads();

    // ---- backtrace: 2 steps per dependent LDS read (lane 0 of wave 0) ----
    if (tid == 0) {
        int s = start, tc = ss - 1;
        st_lds[tc] = (unsigned short)s;
        if ((tc & 1) == 0 && tc >= 1) {            // raw single step on even row tc
            int arg;
            if (s == 256) arg = (g4pack[tc >> 3] >> (tc & 7)) & 1;
            else arg = (BPBYTE(tc, s >> 2) >> ((s & 3) * 2)) & 3;
            s -= arg; --tc; st_lds[tc] = (unsigned short)s;
        }
        while (tc > 1) {                           // tc odd: pair p = tc>>1
            int n;
            if (s == 256) n = bp2_256[tc >> 1];
            else n = (bp2[(tc >> 1) * 64 + (s >> 2)] >> ((s & 3) * 4)) & 0xF;
            int sA = s - (n & 3);
            int sB = sA - (n >> 2);
            st_lds[tc - 1] = (unsigned short)sA;
            st_lds[tc - 2] = (unsigned short)sB;
            s = sB; tc -= 2;
        }
        if (tc == 1) {                             // raw row 1
            int arg;
            if (s == 256) arg = (g4pack[0] >> 1) & 1;
            else arg = (BPBYTE(1, s >> 2) >> ((s & 3) * 2)) & 3;
            s -= arg; st_lds[0] = (unsigned short)s;
        }
    }
    #undef BPBYTE
    __syncthreads();

    // ---- aligned tokens -> collapse repeats -> csum (wave 0) ----
    if (wid == 0) {
        auto tok_lds = [&](int stv) -> int { return (stv & 1) ? ysl[stv >> 1] : bv; };
        const int t0c = lane * 16;
        int prev_raw = (t0c == 0) ? 0 : tok_lds(st_lds[t0c - 1]);
        int cnt = 0;
        int csl[16];
        #pragma unroll
        for (int i = 0; i < 16; ++i) {
            int raw = tok_lds(st_lds[t0c + i]);
            int ac = (raw == prev_raw) ? 0 : raw;
            prev_raw = raw;
            csl[i] = cnt;
            cnt += (ac != bv) ? 1 : 0;
        }
        int v = cnt;
        #pragma unroll
        for (int off = 1; off < 64; off <<= 1) {
            int u = __shfl_up(v, off);
            if (lane >= off) v += u;
        }
        const int base_c = v - cnt;
        int* co = csum_ws + b * XMAX + t0c;
        #pragma unroll
        for (int i = 0; i < 16; ++i) co[i] = base_c + csl[i];
    }
}

// ---------------- Kernel C: trigger mask as 0/1 floats ----------------------
__global__ __launch_bounds__(256) void k_mask(
    const int* __restrict__ csum_ws, const int* __restrict__ src_size,
    float* __restrict__ out)
{
    int bj = blockIdx.x;
    int b = bj / NROWS, j = bj - b * NROWS;
    int ss = src_size[b];
    const int* cs = csum_ws + b * XMAX;
    float* orow = out + 32 + (size_t)bj * XMAX;
    int t = threadIdx.x * 4;
    float4 v;
    float* vp = &v.x;
    #pragma unroll
    for (int i = 0; i < 4; ++i) {
        int tt = t + i;
        int c = cs[tt];
        bool in = tt < ss;
        bool val;
        if (j < YMAX) val = (c == j) && in;
        else          val = ((c == YMAX) || (tt == ss - 1)) && in;
        vp[i] = val ? 1.0f : 0.0f;
    }
    *(float4*)(orow + t) = v;
}

extern "C" void kernel_launch(void* const* d_in, const int* in_sizes, int n_in,
                              void* d_out, int out_size, void* d_ws, size_t ws_size,
                              hipStream_t stream) {
    const float* ctc      = (const float*)d_in[0];
    // d_in[1] = src_mask (derived from src_size; unused)
    const int*   src_size = (const int*)d_in[2];
    const int*   ys       = (const int*)d_in[3];
    const int*   ylens    = (const int*)d_in[4];
    const int*   blankp   = (const int*)d_in[5];
    float* out = (float*)d_out;

    const size_t need = LPWS_BYTES + (size_t)BS * XMAX * sizeof(int);
    if (ws_size >= need) {
        float* lp_ws   = (float*)d_ws;
        int*   csum_ws = (int*)((char*)d_ws + LPWS_BYTES);
        k_gather<<<BS * 16, 256, 0, stream>>>(ctc, src_size, ys, blankp, lp_ws);
        k_viterbi<true><<<BS, 64 * NWAVES, 0, stream>>>(
            ctc, lp_ws, src_size, ys, ylens, blankp, csum_ws, out);
        k_mask<<<BS * NROWS, 256, 0, stream>>>(csum_ws, src_size, out);
    } else {
        int* csum_ws = (int*)d_ws;   // 32*1024*4 = 128 KB
        k_viterbi<false><<<BS, 64 * NWAVES, 0, stream>>>(
            ctc, nullptr, src_size, ys, ylens, blankp, csum_ws, out);
        k_mask<<<BS * NROWS, 256, 0, stream>>>(csum_ws, src_size, out);
    }
}

// Round 5
// 340.319 us; speedup vs baseline: 1.1562x; 1.0492x over previous
//
#include <hip/hip_runtime.h>
#include <stdint.h>

#define LOGZERO (-1e10f)

static constexpr int BS    = 32;
static constexpr int XMAX  = 1024;
static constexpr int VOCAB = 1000;
static constexpr int YMAX  = 128;
static constexpr int NROWS = YMAX + 1;     // 129 trigger-mask rows
static constexpr int CH    = 8;            // rows per LDS chunk (g4pack uses >>3)
static constexpr int NPROD = 8;            // producer waves
static constexpr int NWAVES = 1 + NPROD;   // + 1 consumer wave
static constexpr int NPAIR = XMAX / 2;
static constexpr size_t LPWS_BYTES = (size_t)BS * XMAX * 256 * 4;  // 32 MB staged lp

// lane i <- lane i-1 (mod 64): v_mov_b32_dpp wave_ror:1 (0x13C). Pure VALU —
// replaces ds_bpermute (__shfl) in the recurrence; no lgkmcnt involvement.
__device__ __forceinline__ float rot1(float x) {
    int r = __builtin_amdgcn_update_dpp(0, __float_as_int(x),
                                        0x13C /*wave_ror:1*/, 0xF, 0xF, false);
    return __int_as_float(r);
}

// ---------------- Kernel A: full-chip gather of lp_path ---------------------
__global__ __launch_bounds__(256) void k_gather(
    const float* __restrict__ ctc, const int* __restrict__ src_size,
    const int* __restrict__ ys, const int* __restrict__ blankp,
    float* __restrict__ lp_ws)
{
    const int blk  = blockIdx.x;
    const int b    = blk >> 4;                 // 16 blocks per batch element
    const int seg  = blk & 15;                 // 64-row segment
    const int wid  = threadIdx.x >> 6;
    const int lane = threadIdx.x & 63;
    const int ss   = src_size[b];
    const int bv   = blankp[0];
    const int tokA = ys[b * YMAX + 2 * lane];
    const int tokB = ys[b * YMAX + 2 * lane + 1];
    const float* baseg = ctc + (size_t)b * XMAX * VOCAB;
    float* basew = lp_ws + (size_t)b * XMAX * 256 + lane * 4;
    const int t0 = seg * 64 + wid * 16;
    #pragma unroll 4
    for (int r = 0; r < 16; ++r) {
        const int t = t0 + r;
        if (t < ss) {
            const float* rp = baseg + (size_t)t * VOCAB;
            float vb = rp[bv], va = rp[tokA], vc = rp[tokB];
            *reinterpret_cast<float4*>(basew + (size_t)t * 256) =
                make_float4(vb, va, vb, vc);
        }
    }
}

// One Viterbi step. Value path = pure max/max3 (short serial chain); argmax
// bits derived AFTER by equality, which reproduces the strict-'>' first-max
// tie-break exactly (m is one of its operands; earlier candidate preferred).
// Bits are produced pre-shifted: g0@0-1, g1@2-3, g2@4-5, g3@6-7.
#define VSTEP(qq, PK, SHIFT, RBIT) do {                                     \
    float rot = rot1(a3);                      /* a3[l-1]; lane0<-a3[63] */ \
    float p3  = (lane == 0) ? LZ : rot;                                     \
    float sk1 = al1 ? p3 : LZ;                                              \
    float sk3 = al3 ? a1 : LZ;                                              \
    float m0 = fmaxf(a0, p3);                                               \
    float m1 = fmaxf(fmaxf(a1, a0), sk1);                                   \
    float m2 = fmaxf(a2, a1);                                               \
    float m3 = fmaxf(fmaxf(a3, a2), sk3);                                   \
    unsigned gb = (a0 == m0 ? 0u : 1u)                                      \
                | (a1 == m1 ? 0u : (a0 == m1 ? 4u : 8u))                    \
                | (a2 == m2 ? 0u : 16u)                                     \
                | (a3 == m3 ? 0u : (a2 == m3 ? 64u : 128u));                \
    if (W4) {                                                               \
        float m4 = fmaxf(a4, rot);                                          \
        g4acc |= (a4 == m4 ? 0u : 1u) << (RBIT);                            \
        a4 = m4 + (qq).x;                      /* lp4 == blank lp == q.x */ \
    }                                                                       \
    a0 = m0 + (qq).x; a1 = m1 + (qq).y; a2 = m2 + (qq).z; a3 = m3 + (qq).w; \
    PK |= gb << (SHIFT);                                                    \
} while (0)

// Consumer chunk loop. W4 = track state 256 (only live when plen == 257).
template<bool W4>
__device__ __forceinline__ void viterbi_loop(
    int lane, int ss, bool al1, bool al3, float LZ,
    float (&buf)[2][CH][256], unsigned int* bpb32, unsigned char* g4pack,
    float& a0, float& a1, float& a2, float& a3, float& a4)
{
    const int nfull = ss >> 3;                 // chunks with all 8 steps < ss
    const int mrem  = ss & 7;
    for (int c = 0; c < nfull; ++c) {
        __builtin_amdgcn_s_barrier();          // chunk c published
        asm volatile("" ::: "memory");
        __builtin_amdgcn_sched_barrier(0);
        const int cb = c & 1;
        float4 q[CH];
        #pragma unroll
        for (int r = 0; r < CH; ++r)
            q[r] = *reinterpret_cast<const float4*>(&buf[cb][r][lane * 4]);
        unsigned int pkA = 0, pkB = 0, g4acc = 0;
        #pragma unroll
        for (int r = 0; r < 4; ++r) VSTEP(q[r], pkA, r * 8, r);
        #pragma unroll
        for (int r = 4; r < 8; ++r) VSTEP(q[r], pkB, (r - 4) * 8, r);
        bpb32[(2 * c) * 64 + lane]     = pkA;
        bpb32[(2 * c + 1) * 64 + lane] = pkB;
        if (W4) { if (lane == 0) g4pack[c] = (unsigned char)g4acc; }
    }
    if (mrem) {                                // tail chunk (steps < mrem)
        __builtin_amdgcn_s_barrier();
        asm volatile("" ::: "memory");
        __builtin_amdgcn_sched_barrier(0);
        const int cb = nfull & 1;
        float4 q[CH];
        #pragma unroll
        for (int r = 0; r < CH; ++r)
            q[r] = *reinterpret_cast<const float4*>(&buf[cb][r][lane * 4]);
        unsigned int pkA = 0, pkB = 0, g4acc = 0;
        #pragma unroll
        for (int r = 0; r < 4; ++r)
            if (r < mrem) VSTEP(q[r], pkA, r * 8, r);
        #pragma unroll
        for (int r = 4; r < 8; ++r)
            if (r < mrem) VSTEP(q[r], pkB, (r - 4) * 8, r);
        bpb32[(2 * nfull) * 64 + lane] = pkA;
        if (mrem > 4) bpb32[(2 * nfull + 1) * 64 + lane] = pkB;
        if (W4) { if (lane == 0) g4pack[nfull] = (unsigned char)g4acc; }
    }
}

// ---------------- Kernel B: producer/consumer Viterbi ring -------------------
template<bool STAGED>
__global__ __launch_bounds__(64 * NWAVES) void k_viterbi(
    const float* __restrict__ ctc, const float* __restrict__ lp_ws,
    const int* __restrict__ src_size,
    const int* __restrict__ ys, const int* __restrict__ ylens,
    const int* __restrict__ blankp, int* __restrict__ csum_ws,
    float* __restrict__ out)
{
    __shared__ float buf[2][CH][256];              // 16 KB lp ring
    __shared__ unsigned int  bpb32[(XMAX / 4) * 64]; // 64 KB packed args [t/4][lane]
    __shared__ unsigned char  g4pack[XMAX / CH];   // 128 B state-256 args, packed
    __shared__ unsigned short bp2[NPAIR * 64];     // 64 KB composed pair nibbles
    __shared__ unsigned char  bp2_256[NPAIR];      // 512 B state-256 pairs
    __shared__ unsigned short st_lds[XMAX];        //  2 KB backtraced states
    __shared__ int ysl[YMAX];

    const int b    = blockIdx.x;
    const int tid  = threadIdx.x;
    const int wid  = tid >> 6;
    const int lane = tid & 63;
    const int ss   = src_size[b];
    const int yl   = ylens[b];
    const int bv   = blankp[0];
    const int plen = 2 * yl + 1;
    const float LZ = LOGZERO;

    for (int j = tid; j < YMAX; j += 64 * NWAVES) ysl[j] = ys[b * YMAX + j];
    for (int t = tid; t < XMAX; t += 64 * NWAVES) st_lds[t] = 0;
    __syncthreads();

    const int nchunk = (ss + CH - 1) / CH;
    const float* baseg = ctc + (size_t)b * XMAX * VOCAB;

    int start = 0;   // set by consumer wave, used by lane 0 chain later

    if (wid == 0) {
        // ---------------- consumer ----------------
        const int tokA = ysl[2 * lane];
        const int tokB = ysl[2 * lane + 1];
        const bool al1 = (lane > 0) && (tokA != ysl[2 * lane - 1]);
        const bool al3 = (tokB != tokA);

        float a0 = (lane == 0) ? 0.0f : LZ;
        float a1 = LZ, a2 = LZ, a3 = LZ, a4 = LZ;

        if (plen > 256)
            viterbi_loop<true >(lane, ss, al1, al3, LZ, buf, bpb32, g4pack,
                                a0, a1, a2, a3, a4);
        else
            viterbi_loop<false>(lane, ss, al1, al3, LZ, buf, bpb32, g4pack,
                                a0, a1, a2, a3, a4);

        // score & start (a4 valid on lane 0 only)
        auto getA = [&](int idx) -> float {
            if (idx == 256) return __shfl(a4, 0);
            int k = idx & 3;
            float pick = (k == 0) ? a0 : (k == 1) ? a1 : (k == 2) ? a2 : a3;
            return __shfl(pick, idx >> 2);
        };
        const float s1v = getA(plen - 1), s2v = getA(plen - 2);
        const float score = (s1v > s2v) ? s1v : s2v;
        start = (s1v > s2v) ? (plen - 1) : (plen - 2);
        if (lane == 0) {
            out[b] = score;                                          // output 0
            out[32 + (size_t)BS * NROWS * XMAX + b] = (float)(yl + 1);   // output 2
        }
    } else if (STAGED) {
        // ------- producers: coalesced float4 stream, 4-deep reg prefetch ----
        const int pr = wid - 1;                    // row within chunk
        const float* basew = lp_ws + (size_t)b * XMAX * 256 + lane * 4;
        auto ldrow = [&](int cc) -> float4 {
            int tn = cc * CH + pr; if (tn > XMAX - 1) tn = XMAX - 1;
            return *reinterpret_cast<const float4*>(basew + (size_t)tn * 256);
        };
        float4 v0 = ldrow(0), v1 = ldrow(1), v2 = ldrow(2), v3 = ldrow(3);
        int c = 0;
        for (;;) {
            *reinterpret_cast<float4*>(&buf[c & 1][pr][lane * 4]) = v0;
            v0 = ldrow(c + 4);
            asm volatile("s_waitcnt lgkmcnt(0)" ::: "memory");
            __builtin_amdgcn_s_barrier();
            if (++c >= nchunk) break;
            *reinterpret_cast<float4*>(&buf[c & 1][pr][lane * 4]) = v1;
            v1 = ldrow(c + 4);
            asm volatile("s_waitcnt lgkmcnt(0)" ::: "memory");
            __builtin_amdgcn_s_barrier();
            if (++c >= nchunk) break;
            *reinterpret_cast<float4*>(&buf[c & 1][pr][lane * 4]) = v2;
            v2 = ldrow(c + 4);
            asm volatile("s_waitcnt lgkmcnt(0)" ::: "memory");
            __builtin_amdgcn_s_barrier();
            if (++c >= nchunk) break;
            *reinterpret_cast<float4*>(&buf[c & 1][pr][lane * 4]) = v3;
            v3 = ldrow(c + 4);
            asm volatile("s_waitcnt lgkmcnt(0)" ::: "memory");
            __builtin_amdgcn_s_barrier();
            if (++c >= nchunk) break;
        }
    } else {
        // ------- fallback producers: divergent gather from ctc (round-2) ----
        const int pr = wid - 1;
        const int tokA = ysl[2 * lane];
        const int tokB = ysl[2 * lane + 1];
        int t0 = pr; if (t0 >= ss) t0 = ss - 1;
        const float* r0 = baseg + (size_t)t0 * VOCAB;
        float vb0 = r0[bv], va0 = r0[tokA], vc0 = r0[tokB];
        int t1 = CH + pr; if (t1 >= ss) t1 = ss - 1;
        const float* r1 = baseg + (size_t)t1 * VOCAB;
        float vb1 = r1[bv], va1 = r1[tokA], vc1 = r1[tokB];
        for (int c = 0; c < nchunk; ++c) {
            if (c & 1) {
                *reinterpret_cast<float4*>(&buf[1][pr][lane * 4]) =
                    make_float4(vb1, va1, vb1, vc1);
                int tn = (c + 2) * CH + pr; if (tn >= ss) tn = ss - 1;
                const float* r = baseg + (size_t)tn * VOCAB;
                vb1 = r[bv]; va1 = r[tokA]; vc1 = r[tokB];
            } else {
                *reinterpret_cast<float4*>(&buf[0][pr][lane * 4]) =
                    make_float4(vb0, va0, vb0, vc0);
                int tn = (c + 2) * CH + pr; if (tn >= ss) tn = ss - 1;
                const float* r = baseg + (size_t)tn * VOCAB;
                vb0 = r[bv]; va0 = r[tokA]; vc0 = r[tokB];
            }
            asm volatile("s_waitcnt lgkmcnt(0)" ::: "memory");
            __builtin_amdgcn_s_barrier();
        }
    }
    __syncthreads();   // bpb/g4pack visible to all waves

    // byte (t, laneIdx) of the packed backpointer store
    const unsigned char* bpb8 = reinterpret_cast<const unsigned char*>(bpb32);
    #define BPBYTE(t, l) ((int)bpb8[(((t) >> 2) * 64 + (l)) * 4 + ((t) & 3)])

    // ---- parallel pair-composition across all 9 waves ----
    const int pmax = (ss - 1) >> 1;                // pairs used: p in [1, pmax]
    for (int p = 1 + wid; p <= pmax; p += NWAVES) {
        int oOdd  = BPBYTE(2 * p + 1, lane);
        int oEven = BPBYTE(2 * p, lane);
        int uEven = (lane > 0) ? BPBYTE(2 * p, lane - 1) : 0;
        int evenWin = uEven | (oEven << 8);        // states 4l-4..4l+3 of even row
        unsigned int acc = 0;
        #pragma unroll
        for (int k = 0; k < 4; ++k) {
            int a1v = (oOdd >> (2 * k)) & 3;
            int sh  = 2 * k - 2 * a1v + 8;         // bit pos of state s-a1 in window
            int a2v = (evenWin >> sh) & 3;
            acc |= (unsigned)(a1v | (a2v << 2)) << (4 * k);
        }
        bp2[p * 64 + lane] = (unsigned short)acc;
        const int tOdd = 2 * p + 1, tEven = 2 * p;
        int a16 = (g4pack[tOdd >> 3] >> (tOdd & 7)) & 1;
        int a26 = (a16 == 0) ? ((g4pack[tEven >> 3] >> (tEven & 7)) & 1)
                             : ((BPBYTE(tEven, 63) >> 6) & 3);
        if (lane == 0) bp2_256[p] = (unsigned char)(a16 | (a26 << 2));
    }
    __syncthreads();

    // ---- backtrace: 2 steps per dependent LDS read (lane 0 of wave 0) ----
    if (tid == 0) {
        int s = start, tc = ss - 1;
        st_lds[tc] = (unsigned short)s;
        if ((tc & 1) == 0 && tc >= 1) {            // raw single step on even row tc
            int arg;
            if (s == 256) arg = (g4pack[tc >> 3] >> (tc & 7)) & 1;
            else arg = (BPBYTE(tc, s >> 2) >> ((s & 3) * 2)) & 3;
            s -= arg; --tc; st_lds[tc] = (unsigned short)s;
        }
        while (tc > 1) {                           // tc odd: pair p = tc>>1
            int n;
            if (s == 256) n = bp2_256[tc >> 1];
            else n = (bp2[(tc >> 1) * 64 + (s >> 2)] >> ((s & 3) * 4)) & 0xF;
            int sA = s - (n & 3);
            int sB = sA - (n >> 2);
            st_lds[tc - 1] = (unsigned short)sA;
            st_lds[tc - 2] = (unsigned short)sB;
            s = sB; tc -= 2;
        }
        if (tc == 1) {                             // raw row 1
            int arg;
            if (s == 256) arg = (g4pack[0] >> 1) & 1;
            else arg = (BPBYTE(1, s >> 2) >> ((s & 3) * 2)) & 3;
            s -= arg; st_lds[0] = (unsigned short)s;
        }
    }
    #undef BPBYTE
    __syncthreads();

    // ---- aligned tokens -> collapse repeats -> csum (wave 0) ----
    if (wid == 0) {
        auto tok_lds = [&](int stv) -> int { return (stv & 1) ? ysl[stv >> 1] : bv; };
        const int t0c = lane * 16;
        int prev_raw = (t0c == 0) ? 0 : tok_lds(st_lds[t0c - 1]);
        int cnt = 0;
        int csl[16];
        #pragma unroll
        for (int i = 0; i < 16; ++i) {
            int raw = tok_lds(st_lds[t0c + i]);
            int ac = (raw == prev_raw) ? 0 : raw;
            prev_raw = raw;
            csl[i] = cnt;
            cnt += (ac != bv) ? 1 : 0;
        }
        int v = cnt;
        #pragma unroll
        for (int off = 1; off < 64; off <<= 1) {
            int u = __shfl_up(v, off);
            if (lane >= off) v += u;
        }
        const int base_c = v - cnt;
        int* co = csum_ws + b * XMAX + t0c;
        #pragma unroll
        for (int i = 0; i < 16; ++i) co[i] = base_c + csl[i];
    }
}

// ---------------- Kernel C: trigger mask as 0/1 floats ----------------------
__global__ __launch_bounds__(256) void k_mask(
    const int* __restrict__ csum_ws, const int* __restrict__ src_size,
    float* __restrict__ out)
{
    int bj = blockIdx.x;
    int b = bj / NROWS, j = bj - b * NROWS;
    int ss = src_size[b];
    const int* cs = csum_ws + b * XMAX;
    float* orow = out + 32 + (size_t)bj * XMAX;
    int t = threadIdx.x * 4;
    float4 v;
    float* vp = &v.x;
    #pragma unroll
    for (int i = 0; i < 4; ++i) {
        int tt = t + i;
        int c = cs[tt];
        bool in = tt < ss;
        bool val;
        if (j < YMAX) val = (c == j) && in;
        else          val = ((c == YMAX) || (tt == ss - 1)) && in;
        vp[i] = val ? 1.0f : 0.0f;
    }
    *(float4*)(orow + t) = v;
}

extern "C" void kernel_launch(void* const* d_in, const int* in_sizes, int n_in,
                              void* d_out, int out_size, void* d_ws, size_t ws_size,
                              hipStream_t stream) {
    const float* ctc      = (const float*)d_in[0];
    // d_in[1] = src_mask (derived from src_size; unused)
    const int*   src_size = (const int*)d_in[2];
    const int*   ys       = (const int*)d_in[3];
    const int*   ylens    = (const int*)d_in[4];
    const int*   blankp   = (const int*)d_in[5];
    float* out = (float*)d_out;

    const size_t need = LPWS_BYTES + (size_t)BS * XMAX * sizeof(int);
    if (ws_size >= need) {
        float* lp_ws   = (float*)d_ws;
        int*   csum_ws = (int*)((char*)d_ws + LPWS_BYTES);
        k_gather<<<BS * 16, 256, 0, stream>>>(ctc, src_size, ys, blankp, lp_ws);
        k_viterbi<true><<<BS, 64 * NWAVES, 0, stream>>>(
            ctc, lp_ws, src_size, ys, ylens, blankp, csum_ws, out);
        k_mask<<<BS * NROWS, 256, 0, stream>>>(csum_ws, src_size, out);
    } else {
        int* csum_ws = (int*)d_ws;   // 32*1024*4 = 128 KB
        k_viterbi<false><<<BS, 64 * NWAVES, 0, stream>>>(
            ctc, nullptr, src_size, ys, ylens, blankp, csum_ws, out);
        k_mask<<<BS * NROWS, 256, 0, stream>>>(csum_ws, src_size, out);
    }
}